// Round 12
// baseline (188.044 us; speedup 1.0000x reference)
//
#include <hip/hip_runtime.h>
#include <math.h>

#define NN 768
#define KK_TOP 20
#define NBR_K 21

typedef __attribute__((ext_vector_type(8))) short bf16x8;
typedef __attribute__((ext_vector_type(4))) float f32x4;
typedef unsigned short ushort_t;
typedef unsigned int uint_t;

__device__ __forceinline__ ushort_t f2bf(float x) {
    union { float f; uint_t u; } c; c.f = x;
    uint_t r = (c.u + 0x7FFFu + ((c.u >> 16) & 1u)) >> 16;
    return (ushort_t)r;
}
__device__ __forceinline__ float bf2f(ushort_t u) {
    union { uint_t u; float f; } c; c.u = ((uint_t)u) << 16;
    return c.f;
}

struct Params {
    const float *feats, *boxes, *W1, *b1, *W2, *b2;
    const float *g1W, *g1as, *g1ad, *g1b, *g2W, *g2as, *g2ad, *g2b;
    const float *rW1, *rb1, *rW2, *rb2;
    float *out;
    float *fafb, *xp, *relm, *hid, *asrc, *adst, *xp2, *aux2;
    float4 *wgt4; float *w2p, *consts;
    int *nbr;
    ushort_t *featsbf, *btAB, *btG, *btR, *h1bf;
};

// ================= dispatch 1: prep (801 blocks) =================
// b 0..415 transpose-cast; 416..799 feats cast; 800 pack
__global__ __launch_bounds__(256) void k_prep(Params P)
{
    int b = blockIdx.x, t = threadIdx.x;
    if (b == 800) {
        const float* Wg = P.W1 + 2048 * 256;
        float q0 = Wg[t], q1 = Wg[256 + t], q2 = Wg[512 + t], q3 = Wg[768 + t];
        float w2 = P.W2[t];
        P.wgt4[t] = make_float4(q0, q1, q2, q3);
        P.w2p[t] = w2;
        __shared__ float red[256];
        float vals[4] = {q0 * w2, q1 * w2, q2 * w2, q3 * w2};
        for (int d = 0; d < 4; d++) {
            red[t] = vals[d]; __syncthreads();
            for (int s = 128; s > 0; s >>= 1) {
                if (t < s) red[t] += red[t + s];
                __syncthreads();
            }
            if (t == 0) P.consts[d] = red[0];
            __syncthreads();
        }
        return;
    }
    if (b >= 416) {  // feats cast
        int gid = (b - 416) * 2048 + t * 8;
        float4 v0 = *(const float4*)(P.feats + gid);
        float4 v1 = *(const float4*)(P.feats + gid + 4);
        uint4 r;
        r.x = (uint_t)f2bf(v0.x) | ((uint_t)f2bf(v0.y) << 16);
        r.y = (uint_t)f2bf(v0.z) | ((uint_t)f2bf(v0.w) << 16);
        r.z = (uint_t)f2bf(v1.x) | ((uint_t)f2bf(v1.y) << 16);
        r.w = (uint_t)f2bf(v1.z) | ((uint_t)f2bf(v1.w) << 16);
        *(uint4*)(P.featsbf + gid) = r;
        return;
    }
    const float* in; ushort_t* out; int ldN, tk, tn;
    if (b < 64)       { in = P.W1;              out = P.btAB;              ldN = 256;  tn = b & 3;  tk = b >> 2; }
    else if (b < 128) { int i = b - 64;  in = P.W1 + 1024 * 256; out = P.btAB + 256 * 1024; ldN = 256;  tn = i & 3;  tk = i >> 2; }
    else if (b < 384) { int i = b - 128; in = P.g1W;             out = P.btG;               ldN = 1024; tn = i & 15; tk = i >> 4; }
    else              { int i = b - 384; in = P.rW1;             out = P.btR;               ldN = 128;  tn = i & 1;  tk = i >> 1; }

    __shared__ __align__(16) float tile[64][68];
    int k0 = tk * 64, n0 = tn * 64;
#pragma unroll
    for (int it = 0; it < 4; it++) {
        int r = (t >> 4) + it * 16;
        int c = (t & 15) * 4;
        *(float4*)&tile[r][c] = *(const float4*)(in + (size_t)(k0 + r) * ldN + n0 + c);
    }
    __syncthreads();
    int n = t >> 2;
    int kc = (t & 3) * 16;
    uint_t p[8];
#pragma unroll
    for (int h = 0; h < 8; h++) {
        ushort_t lo = f2bf(tile[kc + 2 * h][n]);
        ushort_t hi = f2bf(tile[kc + 2 * h + 1][n]);
        p[h] = (uint_t)lo | ((uint_t)hi << 16);
    }
    ushort_t* dst = out + (size_t)(n0 + n) * 1024 + k0 + kc;
    *(uint4*)dst = make_uint4(p[0], p[1], p[2], p[3]);
    *(uint4*)(dst + 8) = make_uint4(p[4], p[5], p[6], p[7]);
}

// ---------- bf16 MFMA GEMM tile (64x64) ----------
// mode 0: plain. mode 1: + geom rank-4. mode 2: + geom + bias + relu.
__device__ __forceinline__ void mfma_unit(
    int bx, int by, const ushort_t* __restrict__ A, const ushort_t* __restrict__ Bt,
    float* __restrict__ C, int ldc, int mode,
    const float* __restrict__ boxes, const float* __restrict__ Wgeo,
    const float* __restrict__ bias, int t, char* smem)
{
    ushort_t (*As)[72] = (ushort_t(*)[72])smem;
    ushort_t (*Bs)[72] = (ushort_t(*)[72])(smem + 64 * 72 * 2);
    int m0 = by * 64, n0 = bx * 64;
    int lane = t & 63, w = t >> 6;
    int quad = lane >> 4, ci = lane & 15;

    int r0 = t >> 3, q0 = t & 7;
    int r1 = (t + 256) >> 3, q1 = (t + 256) & 7;

    const ushort_t* Abase = A + (size_t)(m0 + r0) * 1024 + q0 * 8;
    const ushort_t* Abase1 = A + (size_t)(m0 + r1) * 1024 + q1 * 8;
    const ushort_t* Bbase = Bt + (size_t)(n0 + r0) * 1024 + q0 * 8;
    const ushort_t* Bbase1 = Bt + (size_t)(n0 + r1) * 1024 + q1 * 8;

    uint4 pa0 = *(const uint4*)(Abase);
    uint4 pa1 = *(const uint4*)(Abase1);
    uint4 pb0 = *(const uint4*)(Bbase);
    uint4 pb1 = *(const uint4*)(Bbase1);

    f32x4 acc[2][2];
    acc[0][0] = (f32x4){0.f, 0.f, 0.f, 0.f};
    acc[0][1] = (f32x4){0.f, 0.f, 0.f, 0.f};
    acc[1][0] = (f32x4){0.f, 0.f, 0.f, 0.f};
    acc[1][1] = (f32x4){0.f, 0.f, 0.f, 0.f};

    int arow = (w & 1) * 32 + ci;
    int brow = (w >> 1) * 32 + ci;

    for (int kt = 0; kt < 16; kt++) {
        *(uint4*)&As[r0][q0 * 8] = pa0;
        *(uint4*)&As[r1][q1 * 8] = pa1;
        *(uint4*)&Bs[r0][q0 * 8] = pb0;
        *(uint4*)&Bs[r1][q1 * 8] = pb1;
        __syncthreads();
        if (kt < 15) {
            int ko = (kt + 1) * 64;
            pa0 = *(const uint4*)(Abase + ko);
            pa1 = *(const uint4*)(Abase1 + ko);
            pb0 = *(const uint4*)(Bbase + ko);
            pb1 = *(const uint4*)(Bbase1 + ko);
        }
#pragma unroll
        for (int s = 0; s < 2; s++) {
            int kb = s * 32 + quad * 8;
            bf16x8 a0 = *(const bf16x8*)&As[arow][kb];
            bf16x8 a1 = *(const bf16x8*)&As[arow + 16][kb];
            bf16x8 b0 = *(const bf16x8*)&Bs[brow][kb];
            bf16x8 b1 = *(const bf16x8*)&Bs[brow + 16][kb];
            acc[0][0] = __builtin_amdgcn_mfma_f32_16x16x32_bf16(a0, b0, acc[0][0], 0, 0, 0);
            acc[0][1] = __builtin_amdgcn_mfma_f32_16x16x32_bf16(a0, b1, acc[0][1], 0, 0, 0);
            acc[1][0] = __builtin_amdgcn_mfma_f32_16x16x32_bf16(a1, b0, acc[1][0], 0, 0, 0);
            acc[1][1] = __builtin_amdgcn_mfma_f32_16x16x32_bf16(a1, b1, acc[1][1], 0, 0, 0);
        }
        __syncthreads();
    }

    const float inv800 = 1.0f / 800.0f;
#pragma unroll
    for (int ni = 0; ni < 2; ni++) {
        int col = n0 + (w >> 1) * 32 + ni * 16 + ci;
        float wg0 = 0.f, wg1 = 0.f, wg2 = 0.f, wg3 = 0.f, bv = 0.f;
        if (mode) {
            wg0 = Wgeo[col]; wg1 = Wgeo[ldc + col];
            wg2 = Wgeo[2 * ldc + col]; wg3 = Wgeo[3 * ldc + col];
            if (mode == 2) bv = bias[col];
        }
#pragma unroll
        for (int mi = 0; mi < 2; mi++) {
            int rbase = m0 + (w & 1) * 32 + mi * 16 + quad * 4;
#pragma unroll
            for (int reg = 0; reg < 4; reg++) {
                int row = rbase + reg;
                float v = acc[mi][ni][reg];
                if (mode) {
                    float4 bx4 = *(const float4*)(boxes + row * 4);
                    v += (bx4.x * wg0 + bx4.y * wg1 + bx4.z * wg2 + bx4.w * wg3) * inv800 + bv;
                    if (mode == 2) v = fmaxf(v, 0.f);
                }
                C[(size_t)row * ldc + col] = v;
            }
        }
    }
}

// ================= dispatch 2: GEMMs only (288 blocks) =================
__global__ __launch_bounds__(256) void k_gemms(Params P)
{
    __shared__ __align__(16) char smem[18432];
    int u = blockIdx.x, t = threadIdx.x;
    if (u < 96) {
        mfma_unit(u & 7, u >> 3, P.featsbf, P.btAB, P.fafb, 512, 0,
                  nullptr, nullptr, nullptr, t, smem);
    } else {
        int v = u - 96;
        mfma_unit(v & 15, v >> 4, P.featsbf, P.btG, P.xp, 1024, 1,
                  P.boxes, P.g1W + (size_t)1024 * 1024, nullptr, t, smem);
    }
}

// ================= dispatch 3: rel (576) + attn_coef (768) =================
// rel folds Arow/Brow into its hc loop: sum fas*w2 = Arow+c4 (b1 pre-added), sum fbs*w2 = Brow.
#define REL_ACC(FA0, FA1, FB0, FB1, Q, W)                                           \
    {                                                                               \
        float v;                                                                    \
        v = FA0 + FB0;                                                              \
        v = fmaf(g00.x, Q.x, v); v = fmaf(g00.y, Q.y, v);                           \
        v = fmaf(g00.z, Q.z, v); v = fmaf(g00.w, Q.w, v);                           \
        acc00 = fmaf(fabsf(v), W, acc00);                                           \
        v = FA0 + FB1;                                                              \
        v = fmaf(g01.x, Q.x, v); v = fmaf(g01.y, Q.y, v);                           \
        v = fmaf(g01.z, Q.z, v); v = fmaf(g01.w, Q.w, v);                           \
        acc01 = fmaf(fabsf(v), W, acc01);                                           \
        v = FA1 + FB0;                                                              \
        v = fmaf(g10.x, Q.x, v); v = fmaf(g10.y, Q.y, v);                           \
        v = fmaf(g10.z, Q.z, v); v = fmaf(g10.w, Q.w, v);                           \
        acc10 = fmaf(fabsf(v), W, acc10);                                           \
        v = FA1 + FB1;                                                              \
        v = fmaf(g11.x, Q.x, v); v = fmaf(g11.y, Q.y, v);                           \
        v = fmaf(g11.z, Q.z, v); v = fmaf(g11.w, Q.w, v);                           \
        acc11 = fmaf(fabsf(v), W, acc11);                                           \
        sA0 = fmaf(FA0, W, sA0); sA1 = fmaf(FA1, W, sA1);                           \
        sB0 = fmaf(FB0, W, sB0); sB1 = fmaf(FB1, W, sB1);                           \
    }

__global__ __launch_bounds__(256) void k_rel(Params P)
{
    int t = threadIdx.x;
    int u = blockIdx.x;
    if (u >= 576) {
        // attn_coef: one wave per (n,h), reads xp directly
        int wv = (u - 576) * 4 + (t >> 6);
        int lane = t & 63;
        int n = wv >> 2, h = wv & 3;
        const float4* xr = (const float4*)(P.xp + (size_t)n * 1024 + h * 256);
        const float4* wsrc = (const float4*)(P.g1as + h * 256);
        const float4* wdst = (const float4*)(P.g1ad + h * 256);
        float4 x4 = xr[lane], a4 = wsrc[lane], b4 = wdst[lane];
        float s1 = x4.x * a4.x + x4.y * a4.y + x4.z * a4.z + x4.w * a4.w;
        float s2 = x4.x * b4.x + x4.y * b4.y + x4.z * b4.z + x4.w * b4.w;
#pragma unroll
        for (int off = 32; off > 0; off >>= 1) {
            s1 += __shfl_xor(s1, off);
            s2 += __shfl_xor(s2, off);
        }
        if (lane == 0) { P.asrc[wv] = s1; P.adst[wv] = s2; }
        return;
    }

    __shared__ __align__(16) float fas[32][68];
    __shared__ __align__(16) float fbs[32][68];
    int bx = u % 24, by = u / 24;
    int tx = t & 15, ty = t >> 4;
    int i0 = by * 32, j0 = bx * 32;
    int ia = i0 + ty, ib = i0 + ty + 16;
    int ja = j0 + tx, jb = j0 + tx + 16;

    float4 Bi0 = *(const float4*)(P.boxes + ia * 4);
    float4 Bi1 = *(const float4*)(P.boxes + ib * 4);
    float4 Bj0 = *(const float4*)(P.boxes + ja * 4);
    float4 Bj1 = *(const float4*)(P.boxes + jb * 4);
    float4 g00 = make_float4(fabsf(Bi0.x - Bj0.x), fabsf(Bi0.y - Bj0.y), fabsf(Bi0.z - Bj0.z), fabsf(Bi0.w - Bj0.w));
    float4 g01 = make_float4(fabsf(Bi0.x - Bj1.x), fabsf(Bi0.y - Bj1.y), fabsf(Bi0.z - Bj1.z), fabsf(Bi0.w - Bj1.w));
    float4 g10 = make_float4(fabsf(Bi1.x - Bj0.x), fabsf(Bi1.y - Bj0.y), fabsf(Bi1.z - Bj0.z), fabsf(Bi1.w - Bj0.w));
    float4 g11 = make_float4(fabsf(Bi1.x - Bj1.x), fabsf(Bi1.y - Bj1.y), fabsf(Bi1.z - Bj1.z), fabsf(Bi1.w - Bj1.w));

    float acc00 = 0.f, acc01 = 0.f, acc10 = 0.f, acc11 = 0.f;
    float sA0 = 0.f, sA1 = 0.f, sB0 = 0.f, sB1 = 0.f;

    for (int p = 0; p < 4; p++) {
        for (int e = t; e < 512; e += 256) {
            int r = e >> 4, cq = e & 15;
            float4 bb = *(const float4*)(P.b1 + p * 64 + cq * 4);
            float4 fv = *(const float4*)(P.fafb + (size_t)(i0 + r) * 512 + p * 64 + cq * 4);
            float4 gv = *(const float4*)(P.fafb + (size_t)(j0 + r) * 512 + 256 + p * 64 + cq * 4);
            *(float4*)&fas[r][cq * 4] = make_float4(fv.x + bb.x, fv.y + bb.y, fv.z + bb.z, fv.w + bb.w);
            *(float4*)&fbs[r][cq * 4] = gv;
        }
        __syncthreads();
        const float4* wg = P.wgt4 + p * 64;
        const float* w2 = P.w2p + p * 64;
#pragma unroll 8
        for (int hc = 0; hc < 16; hc++) {
            int h4 = hc * 4;
            float4 fa0 = *(const float4*)&fas[ty][h4];
            float4 fa1 = *(const float4*)&fas[ty + 16][h4];
            float4 fb0 = *(const float4*)&fbs[tx][h4];
            float4 fb1 = *(const float4*)&fbs[tx + 16][h4];
            float4 w2v = *(const float4*)(w2 + h4);
            float4 q0 = wg[h4], q1 = wg[h4 + 1], q2 = wg[h4 + 2], q3 = wg[h4 + 3];
            REL_ACC(fa0.x, fa1.x, fb0.x, fb1.x, q0, w2v.x);
            REL_ACC(fa0.y, fa1.y, fb0.y, fb1.y, q1, w2v.y);
            REL_ACC(fa0.z, fa1.z, fb0.z, fb1.z, q2, w2v.z);
            REL_ACC(fa0.w, fa1.w, fb0.w, fb1.w, q3, w2v.w);
        }
        __syncthreads();
    }

    float c0 = P.consts[0], c1 = P.consts[1], c2 = P.consts[2], c3 = P.consts[3];
    float b2v = P.b2[0];

    float lin, r00, r01, r10, r11;
    lin = sA0 + sB0 + g00.x * c0 + g00.y * c1 + g00.z * c2 + g00.w * c3;
    r00 = 0.5f * (lin + acc00) + b2v;
    lin = sA0 + sB1 + g01.x * c0 + g01.y * c1 + g01.z * c2 + g01.w * c3;
    r01 = 0.5f * (lin + acc01) + b2v;
    lin = sA1 + sB0 + g10.x * c0 + g10.y * c1 + g10.z * c2 + g10.w * c3;
    r10 = 0.5f * (lin + acc10) + b2v;
    lin = sA1 + sB1 + g11.x * c0 + g11.y * c1 + g11.z * c2 + g11.w * c3;
    r11 = 0.5f * (lin + acc11) + b2v;
    P.relm[(size_t)ia * NN + ja] = (ia == ja) ? -1e9f : r00;
    P.relm[(size_t)ia * NN + jb] = (ia == jb) ? -1e9f : r01;
    P.relm[(size_t)ib * NN + ja] = (ib == ja) ? -1e9f : r10;
    P.relm[(size_t)ib * NN + jb] = (ib == jb) ? -1e9f : r11;
}

// ================= dispatch 4: topk + gat1, block per node =================
__global__ __launch_bounds__(256) void k_topkgat1(Params P)
{
    int n = blockIdx.x, t = threadIdx.x;
    __shared__ int nb[NBR_K];
    __shared__ float alpha[NBR_K][4];

    if (t < 64) {
        int lane = t;
        const float* rp = P.relm + (size_t)n * NN;
        float v[12];
#pragma unroll
        for (int q = 0; q < 12; q++) v[q] = rp[q * 64 + lane];
        for (int kk = 0; kk < KK_TOP; kk++) {
            float best = v[0]; int bq = 0;
#pragma unroll
            for (int q = 1; q < 12; q++) {
                if (v[q] > best) { best = v[q]; bq = q; }
            }
            int bidx = bq * 64 + lane;
#pragma unroll
            for (int off = 32; off > 0; off >>= 1) {
                float ov = __shfl_xor(best, off);
                int oi = __shfl_xor(bidx, off);
                if (ov > best || (ov == best && oi < bidx)) { best = ov; bidx = oi; }
            }
            if (lane == 0) { nb[kk] = bidx; P.nbr[n * NBR_K + kk] = bidx; }
            int bl = bidx & 63, bq2 = bidx >> 6;
            if (lane == bl) {
#pragma unroll
                for (int q = 0; q < 12; q++)
                    if (q == bq2) v[q] = -INFINITY;
            }
        }
        if (lane == 0) { nb[KK_TOP] = n; P.nbr[n * NBR_K + KK_TOP] = n; }
    }
    __syncthreads();

    if (t < NBR_K * 4) {
        int k = t % NBR_K, h = t / NBR_K;
        float e = P.asrc[nb[k] * 4 + h] + P.adst[n * 4 + h];
        e = (e > 0.f) ? e : 0.2f * e;
        alpha[k][h] = e;
    }
    __syncthreads();
    if (t < 4) {
        float m = -INFINITY;
        for (int k = 0; k < NBR_K; k++) m = fmaxf(m, alpha[k][t]);
        float s = 0.f;
        for (int k = 0; k < NBR_K; k++) { float ex = expf(alpha[k][t] - m); alpha[k][t] = ex; s += ex; }
        float inv = 1.f / s;
        for (int k = 0; k < NBR_K; k++) alpha[k][t] *= inv;
    }
    __syncthreads();

    int h = t >> 6;
    float ax = 0.f, ay = 0.f, az = 0.f, aw = 0.f;
#pragma unroll 7
    for (int k = 0; k < NBR_K; k++) {
        float a = alpha[k][h];
        float4 xv = ((const float4*)(P.xp + (size_t)nb[k] * 1024))[t];
        ax = fmaf(a, xv.x, ax); ay = fmaf(a, xv.y, ay);
        az = fmaf(a, xv.z, az); aw = fmaf(a, xv.w, aw);
    }
    float4 gb = ((const float4*)P.g1b)[t];
    uint2 pk;
    pk.x = (uint_t)f2bf(fmaxf(ax + gb.x, 0.f)) | ((uint_t)f2bf(fmaxf(ay + gb.y, 0.f)) << 16);
    pk.y = (uint_t)f2bf(fmaxf(az + gb.z, 0.f)) | ((uint_t)f2bf(fmaxf(aw + gb.w, 0.f)) << 16);
    *(uint2*)(P.h1bf + (size_t)n * 1024 + t * 4) = pk;
}

// ================= dispatch 5: gat2a (192) + G3 via mfma_unit (24) =================
__global__ __launch_bounds__(256) void k_p6(Params P)
{
    __shared__ __align__(16) char smem[18432];
    int u = blockIdx.x, t = threadIdx.x;
    if (u < 192) {
        int wid = u * 4 + (t >> 6);
        int lane = t & 63;
        float s0 = 0.f, s1 = 0.f;
#pragma unroll
        for (int it = 0; it < 4; it++) {
            int k = it * 256 + lane * 4;
            uint2 pk = *(const uint2*)(P.h1bf + (size_t)wid * 1024 + k);
            float v0 = bf2f((ushort_t)(pk.x & 0xFFFF));
            float v1 = bf2f((ushort_t)(pk.x >> 16));
            float v2 = bf2f((ushort_t)(pk.y & 0xFFFF));
            float v3 = bf2f((ushort_t)(pk.y >> 16));
            float4 w0 = *(const float4*)(P.g2W + k * 2);
            float4 w1 = *(const float4*)(P.g2W + k * 2 + 4);
            s0 += v0 * w0.x + v1 * w0.z + v2 * w1.x + v3 * w1.z;
            s1 += v0 * w0.y + v1 * w0.w + v2 * w1.y + v3 * w1.w;
        }
#pragma unroll
        for (int off = 32; off > 0; off >>= 1) { s0 += __shfl_down(s0, off); s1 += __shfl_down(s1, off); }
        if (lane == 0) {
            P.xp2[wid * 2 + 0] = s0; P.xp2[wid * 2 + 1] = s1;
            P.aux2[wid * 2 + 0] = s0 * P.g2as[0] + s1 * P.g2as[1];
            P.aux2[wid * 2 + 1] = s0 * P.g2ad[0] + s1 * P.g2ad[1];
        }
    } else {
        int v = u - 192;
        mfma_unit(v & 1, v >> 1, P.h1bf, P.btR, P.hid, 128, 2,
                  P.boxes, P.rW1 + (size_t)1024 * 128, P.rb1, t, smem);
    }
}

// ================= dispatch 6: gat2b wave-per-node (192) + decode (3) =================
__global__ __launch_bounds__(256) void k_p7(Params P)
{
    __shared__ __align__(16) float rw2s[512];
    int u = blockIdx.x, t = threadIdx.x;
    if (u < 192) {
        int n = u * 4 + (t >> 6);
        int lane = t & 63;
        float adstv = P.aux2[n * 2 + 1];
        float e = -INFINITY, x0 = 0.f, x1 = 0.f;
        if (lane < NBR_K) {
            int nbk = P.nbr[n * NBR_K + lane];
            float vv = P.aux2[nbk * 2 + 0] + adstv;
            e = (vv > 0.f) ? vv : 0.2f * vv;
            x0 = P.xp2[nbk * 2 + 0];
            x1 = P.xp2[nbk * 2 + 1];
        }
        float m = e;
#pragma unroll
        for (int off = 32; off > 0; off >>= 1) m = fmaxf(m, __shfl_xor(m, off));
        float ex = (lane < NBR_K) ? expf(e - m) : 0.f;
        float ssum = ex, o0 = ex * x0, o1 = ex * x1;
#pragma unroll
        for (int off = 32; off > 0; off >>= 1) {
            ssum += __shfl_xor(ssum, off);
            o0 += __shfl_xor(o0, off);
            o1 += __shfl_xor(o1, off);
        }
        if (lane == 0) {
            float inv = 1.f / ssum;
            P.out[n * 6 + 0] = o0 * inv + P.g2b[0];
            P.out[n * 6 + 1] = o1 * inv + P.g2b[1];
        }
        return;
    }
    // decode: thread per node, rW2 staged in LDS
    *(float2*)&rw2s[t * 2] = *(const float2*)(P.rW2 + t * 2);
    __syncthreads();
    int n = (u - 192) * 256 + t;
    const float4* hrow = (const float4*)(P.hid + (size_t)n * 128);
    float d0 = 0.f, d1 = 0.f, d2 = 0.f, d3 = 0.f;
#pragma unroll 8
    for (int k4 = 0; k4 < 32; k4++) {
        float4 h = hrow[k4];
        const float* wv = &rw2s[k4 * 16];
        d0 = fmaf(h.x, wv[0], d0);  d1 = fmaf(h.x, wv[1], d1);
        d2 = fmaf(h.x, wv[2], d2);  d3 = fmaf(h.x, wv[3], d3);
        d0 = fmaf(h.y, wv[4], d0);  d1 = fmaf(h.y, wv[5], d1);
        d2 = fmaf(h.y, wv[6], d2);  d3 = fmaf(h.y, wv[7], d3);
        d0 = fmaf(h.z, wv[8], d0);  d1 = fmaf(h.z, wv[9], d1);
        d2 = fmaf(h.z, wv[10], d2); d3 = fmaf(h.z, wv[11], d3);
        d0 = fmaf(h.w, wv[12], d0); d1 = fmaf(h.w, wv[13], d1);
        d2 = fmaf(h.w, wv[14], d2); d3 = fmaf(h.w, wv[15], d3);
    }
    d0 += P.rb2[0]; d1 += P.rb2[1]; d2 += P.rb2[2]; d3 += P.rb2[3];
    float4 bx = *(const float4*)(P.boxes + n * 4);
    float pw = bx.z - bx.x, ph = bx.w - bx.y;
    float pcx = bx.x + 0.5f * pw, pcy = bx.y + 0.5f * ph;
    float gcx = d0 * pw + pcx, gcy = d1 * ph + pcy;
    float gw = expf(d2) * pw, gh = expf(d3) * ph;
    P.out[n * 6 + 2] = gcx - 0.5f * gw;
    P.out[n * 6 + 3] = gcy - 0.5f * gh;
    P.out[n * 6 + 4] = gcx + 0.5f * gw;
    P.out[n * 6 + 5] = gcy + 0.5f * gh;
}

extern "C" void kernel_launch(void* const* d_in, const int* in_sizes, int n_in,
                              void* d_out, int out_size, void* d_ws, size_t ws_size,
                              hipStream_t stream)
{
    Params P;
    P.feats = (const float*)d_in[0];
    P.boxes = (const float*)d_in[1];
    P.W1    = (const float*)d_in[2];
    P.b1    = (const float*)d_in[3];
    P.W2    = (const float*)d_in[4];
    P.b2    = (const float*)d_in[5];
    P.g1W   = (const float*)d_in[6];
    P.g1as  = (const float*)d_in[7];
    P.g1ad  = (const float*)d_in[8];
    P.g1b   = (const float*)d_in[9];
    P.g2W   = (const float*)d_in[10];
    P.g2as  = (const float*)d_in[11];
    P.g2ad  = (const float*)d_in[12];
    P.g2b   = (const float*)d_in[13];
    P.rW1   = (const float*)d_in[14];
    P.rb1   = (const float*)d_in[15];
    P.rW2   = (const float*)d_in[16];
    P.rb2   = (const float*)d_in[17];
    P.out   = (float*)d_out;

    float* ws = (float*)d_ws;
    P.fafb  = ws;                      // 768*512
    P.xp    = P.fafb + 393216;         // 768*1024
    P.relm  = P.xp + 786432;           // 768*768
    P.hid   = P.relm + 589824;         // 768*128
    P.asrc  = P.hid + 98304;           // 3072
    P.adst  = P.asrc + 3072;           // 3072
    P.xp2   = P.adst + 3072;           // 1536
    P.aux2  = P.xp2 + 1536;            // 1536
    P.wgt4  = (float4*)(P.aux2 + 1536);// 256 float4
    P.w2p   = (float*)(P.wgt4 + 256);  // 256
    P.consts= P.w2p + 256;             // 8
    P.nbr   = (int*)(P.consts + 8);    // 768*21
    P.featsbf = (ushort_t*)(P.nbr + 16128);  // 768*1024
    P.btAB    = P.featsbf + 786432;          // 512*1024
    P.btG     = P.btAB + 524288;             // 1024*1024
    P.btR     = P.btG + 1048576;             // 128*1024
    P.h1bf    = P.btR + 131072;              // 768*1024

    k_prep    <<<dim3(801),  dim3(256), 0, stream>>>(P);
    k_gemms   <<<dim3(288),  dim3(256), 0, stream>>>(P);
    k_rel     <<<dim3(1344), dim3(256), 0, stream>>>(P);
    k_topkgat1<<<dim3(768),  dim3(256), 0, stream>>>(P);
    k_p6      <<<dim3(216),  dim3(256), 0, stream>>>(P);
    k_p7      <<<dim3(195),  dim3(256), 0, stream>>>(P);
}

// Round 13
// 176.821 us; speedup vs baseline: 1.0635x; 1.0635x over previous
//
#include <hip/hip_runtime.h>
#include <math.h>

#define NN 768
#define KK_TOP 20
#define NBR_K 21

typedef __attribute__((ext_vector_type(8))) short bf16x8;
typedef __attribute__((ext_vector_type(4))) float f32x4;
typedef unsigned short ushort_t;
typedef unsigned int uint_t;

__device__ __forceinline__ ushort_t f2bf(float x) {
    union { float f; uint_t u; } c; c.f = x;
    uint_t r = (c.u + 0x7FFFu + ((c.u >> 16) & 1u)) >> 16;
    return (ushort_t)r;
}
__device__ __forceinline__ float bf2f(ushort_t u) {
    union { uint_t u; float f; } c; c.u = ((uint_t)u) << 16;
    return c.f;
}

struct Params {
    const float *feats, *boxes, *W1, *b1, *W2, *b2;
    const float *g1W, *g1as, *g1ad, *g1b, *g2W, *g2as, *g2ad, *g2b;
    const float *rW1, *rb1, *rW2, *rb2;
    float *out;
    float *fafb, *xp, *relm, *hid, *Arow, *Brow, *asrc, *adst, *xp2, *aux2;
    float4 *wgt4; float *w2p, *consts;
    float *va, *vb, *av;
    int *nbr;
    ushort_t *featsbf, *btAB, *btG, *btR, *h1bf;
};

// ================= dispatch 1: prep =================
// b 0..415 transpose-cast; 416..799 feats cast; 800 pack;
// 801..1312 va/vb wave-units; 1313..3368 av wave-units
__global__ __launch_bounds__(256) void k_prep(Params P)
{
    int b = blockIdx.x, t = threadIdx.x;
    if (b == 800) {
        const float* Wg = P.W1 + 2048 * 256;
        float q0 = Wg[t], q1 = Wg[256 + t], q2 = Wg[512 + t], q3 = Wg[768 + t];
        float w2 = P.W2[t];
        P.wgt4[t] = make_float4(q0, q1, q2, q3);
        P.w2p[t] = w2;
        __shared__ float red[256];
        float vals[5] = {q0 * w2, q1 * w2, q2 * w2, q3 * w2, P.b1[t] * w2};
        for (int d = 0; d < 5; d++) {
            red[t] = vals[d]; __syncthreads();
            for (int s = 128; s > 0; s >>= 1) {
                if (t < s) red[t] += red[t + s];
                __syncthreads();
            }
            if (t == 0) P.consts[d] = red[0];
            __syncthreads();
        }
        return;
    }
    if (b >= 1313) {  // av wave-units
        int o = (b - 1313) * 4 + (t >> 6);
        int lane = t & 63;
        if (o >= 8224) return;
        int vec = o / 1028, k = o - vec * 1028;
        int h = vec & 3;
        const float4* aw = (const float4*)(((vec < 4) ? P.g1as : P.g1ad) + h * 256);
        const float4* gw = (const float4*)(P.g1W + (size_t)k * 1024 + h * 256);
        float4 a = aw[lane], g = gw[lane];
        float s = a.x * g.x + a.y * g.y + a.z * g.z + a.w * g.w;
#pragma unroll
        for (int off = 32; off > 0; off >>= 1) s += __shfl_xor(s, off);
        if (lane == 0) P.av[o] = s;
        return;
    }
    if (b >= 801) {  // va/vb wave-units
        int o = (b - 801) * 4 + (t >> 6);
        int lane = t & 63;
        const float4* row = (const float4*)(P.W1 + (size_t)o * 256);
        float4 w = ((const float4*)P.W2)[lane];
        float4 f = row[lane];
        float s = f.x * w.x + f.y * w.y + f.z * w.z + f.w * w.w;
#pragma unroll
        for (int off = 32; off > 0; off >>= 1) s += __shfl_xor(s, off);
        if (lane == 0) { if (o < 1024) P.va[o] = s; else P.vb[o - 1024] = s; }
        return;
    }
    if (b >= 416) {  // feats cast
        int gid = (b - 416) * 2048 + t * 8;
        float4 v0 = *(const float4*)(P.feats + gid);
        float4 v1 = *(const float4*)(P.feats + gid + 4);
        uint4 r;
        r.x = (uint_t)f2bf(v0.x) | ((uint_t)f2bf(v0.y) << 16);
        r.y = (uint_t)f2bf(v0.z) | ((uint_t)f2bf(v0.w) << 16);
        r.z = (uint_t)f2bf(v1.x) | ((uint_t)f2bf(v1.y) << 16);
        r.w = (uint_t)f2bf(v1.z) | ((uint_t)f2bf(v1.w) << 16);
        *(uint4*)(P.featsbf + gid) = r;
        return;
    }
    const float* in; ushort_t* out; int ldN, tk, tn;
    if (b < 64)       { in = P.W1;              out = P.btAB;              ldN = 256;  tn = b & 3;  tk = b >> 2; }
    else if (b < 128) { int i = b - 64;  in = P.W1 + 1024 * 256; out = P.btAB + 256 * 1024; ldN = 256;  tn = i & 3;  tk = i >> 2; }
    else if (b < 384) { int i = b - 128; in = P.g1W;             out = P.btG;               ldN = 1024; tn = i & 15; tk = i >> 4; }
    else              { int i = b - 384; in = P.rW1;             out = P.btR;               ldN = 128;  tn = i & 1;  tk = i >> 1; }

    __shared__ __align__(16) float tile[64][68];
    int k0 = tk * 64, n0 = tn * 64;
#pragma unroll
    for (int it = 0; it < 4; it++) {
        int r = (t >> 4) + it * 16;
        int c = (t & 15) * 4;
        *(float4*)&tile[r][c] = *(const float4*)(in + (size_t)(k0 + r) * ldN + n0 + c);
    }
    __syncthreads();
    int n = t >> 2;
    int kc = (t & 3) * 16;
    uint_t p[8];
#pragma unroll
    for (int h = 0; h < 8; h++) {
        ushort_t lo = f2bf(tile[kc + 2 * h][n]);
        ushort_t hi = f2bf(tile[kc + 2 * h + 1][n]);
        p[h] = (uint_t)lo | ((uint_t)hi << 16);
    }
    ushort_t* dst = out + (size_t)(n0 + n) * 1024 + k0 + kc;
    *(uint4*)dst = make_uint4(p[0], p[1], p[2], p[3]);
    *(uint4*)(dst + 8) = make_uint4(p[4], p[5], p[6], p[7]);
}

// ---------- bf16 MFMA GEMM tile (64x64) ----------
// mode 0: plain. mode 1: + geom rank-4. mode 2: + geom + bias + relu.
__device__ __forceinline__ void mfma_unit(
    int bx, int by, const ushort_t* __restrict__ A, const ushort_t* __restrict__ Bt,
    float* __restrict__ C, int ldc, int mode,
    const float* __restrict__ boxes, const float* __restrict__ Wgeo,
    const float* __restrict__ bias, int t, char* smem)
{
    ushort_t (*As)[72] = (ushort_t(*)[72])smem;
    ushort_t (*Bs)[72] = (ushort_t(*)[72])(smem + 64 * 72 * 2);
    int m0 = by * 64, n0 = bx * 64;
    int lane = t & 63, w = t >> 6;
    int quad = lane >> 4, ci = lane & 15;

    int r0 = t >> 3, q0 = t & 7;
    int r1 = (t + 256) >> 3, q1 = (t + 256) & 7;

    const ushort_t* Abase = A + (size_t)(m0 + r0) * 1024 + q0 * 8;
    const ushort_t* Abase1 = A + (size_t)(m0 + r1) * 1024 + q1 * 8;
    const ushort_t* Bbase = Bt + (size_t)(n0 + r0) * 1024 + q0 * 8;
    const ushort_t* Bbase1 = Bt + (size_t)(n0 + r1) * 1024 + q1 * 8;

    uint4 pa0 = *(const uint4*)(Abase);
    uint4 pa1 = *(const uint4*)(Abase1);
    uint4 pb0 = *(const uint4*)(Bbase);
    uint4 pb1 = *(const uint4*)(Bbase1);

    f32x4 acc[2][2];
    acc[0][0] = (f32x4){0.f, 0.f, 0.f, 0.f};
    acc[0][1] = (f32x4){0.f, 0.f, 0.f, 0.f};
    acc[1][0] = (f32x4){0.f, 0.f, 0.f, 0.f};
    acc[1][1] = (f32x4){0.f, 0.f, 0.f, 0.f};

    int arow = (w & 1) * 32 + ci;
    int brow = (w >> 1) * 32 + ci;

    for (int kt = 0; kt < 16; kt++) {
        *(uint4*)&As[r0][q0 * 8] = pa0;
        *(uint4*)&As[r1][q1 * 8] = pa1;
        *(uint4*)&Bs[r0][q0 * 8] = pb0;
        *(uint4*)&Bs[r1][q1 * 8] = pb1;
        __syncthreads();
        if (kt < 15) {
            int ko = (kt + 1) * 64;
            pa0 = *(const uint4*)(Abase + ko);
            pa1 = *(const uint4*)(Abase1 + ko);
            pb0 = *(const uint4*)(Bbase + ko);
            pb1 = *(const uint4*)(Bbase1 + ko);
        }
#pragma unroll
        for (int s = 0; s < 2; s++) {
            int kb = s * 32 + quad * 8;
            bf16x8 a0 = *(const bf16x8*)&As[arow][kb];
            bf16x8 a1 = *(const bf16x8*)&As[arow + 16][kb];
            bf16x8 b0 = *(const bf16x8*)&Bs[brow][kb];
            bf16x8 b1 = *(const bf16x8*)&Bs[brow + 16][kb];
            acc[0][0] = __builtin_amdgcn_mfma_f32_16x16x32_bf16(a0, b0, acc[0][0], 0, 0, 0);
            acc[0][1] = __builtin_amdgcn_mfma_f32_16x16x32_bf16(a0, b1, acc[0][1], 0, 0, 0);
            acc[1][0] = __builtin_amdgcn_mfma_f32_16x16x32_bf16(a1, b0, acc[1][0], 0, 0, 0);
            acc[1][1] = __builtin_amdgcn_mfma_f32_16x16x32_bf16(a1, b1, acc[1][1], 0, 0, 0);
        }
        __syncthreads();
    }

    const float inv800 = 1.0f / 800.0f;
#pragma unroll
    for (int ni = 0; ni < 2; ni++) {
        int col = n0 + (w >> 1) * 32 + ni * 16 + ci;
        float wg0 = 0.f, wg1 = 0.f, wg2 = 0.f, wg3 = 0.f, bv = 0.f;
        if (mode) {
            wg0 = Wgeo[col]; wg1 = Wgeo[ldc + col];
            wg2 = Wgeo[2 * ldc + col]; wg3 = Wgeo[3 * ldc + col];
            if (mode == 2) bv = bias[col];
        }
#pragma unroll
        for (int mi = 0; mi < 2; mi++) {
            int rbase = m0 + (w & 1) * 32 + mi * 16 + quad * 4;
#pragma unroll
            for (int reg = 0; reg < 4; reg++) {
                int row = rbase + reg;
                float v = acc[mi][ni][reg];
                if (mode) {
                    float4 bx4 = *(const float4*)(boxes + row * 4);
                    v += (bx4.x * wg0 + bx4.y * wg1 + bx4.z * wg2 + bx4.w * wg3) * inv800 + bv;
                    if (mode == 2) v = fmaxf(v, 0.f);
                }
                C[(size_t)row * ldc + col] = v;
            }
        }
    }
}

// ================= dispatch 2: GEMMs + rowdot + attn =================
__global__ __launch_bounds__(256) void k_gemms(Params P)
{
    __shared__ __align__(16) char smem[18432];
    int u = blockIdx.x, t = threadIdx.x;
    if (u < 96) {
        mfma_unit(u & 7, u >> 3, P.featsbf, P.btAB, P.fafb, 512, 0,
                  nullptr, nullptr, nullptr, t, smem);
    } else if (u < 288) {
        int v = u - 96;
        mfma_unit(v & 15, v >> 4, P.featsbf, P.btG, P.xp, 1024, 1,
                  P.boxes, P.g1W + (size_t)1024 * 1024, nullptr, t, smem);
    } else if (u < 480) {
        int row = (u - 288) * 4 + (t >> 6);
        int lane = t & 63;
        const float4* fr = (const float4*)(P.feats + (size_t)row * 1024);
        const float4* va4 = (const float4*)P.va;
        const float4* vb4 = (const float4*)P.vb;
        float s1 = 0.f, s2 = 0.f;
#pragma unroll
        for (int it = 0; it < 4; it++) {
            int idx = it * 64 + lane;
            float4 f = fr[idx], a = va4[idx], b = vb4[idx];
            s1 += f.x * a.x + f.y * a.y + f.z * a.z + f.w * a.w;
            s2 += f.x * b.x + f.y * b.y + f.z * b.z + f.w * b.w;
        }
#pragma unroll
        for (int off = 32; off > 0; off >>= 1) {
            s1 += __shfl_xor(s1, off);
            s2 += __shfl_xor(s2, off);
        }
        if (lane == 0) { P.Arow[row] = s1; P.Brow[row] = s2; }
    } else {
        int pair = (u - 480) * 4 + (t >> 6);
        int lane = t & 63;
        int n = pair >> 2, h = pair & 3;
        const float4* fr = (const float4*)(P.feats + (size_t)n * 1024);
        const float* vs = P.av + h * 1028;
        const float* vd = P.av + (4 + h) * 1028;
        const float4* vs4 = (const float4*)vs;
        const float4* vd4 = (const float4*)vd;
        float s1 = 0.f, s2 = 0.f;
#pragma unroll
        for (int it = 0; it < 4; it++) {
            int idx = it * 64 + lane;
            float4 f = fr[idx], a = vs4[idx], b = vd4[idx];
            s1 += f.x * a.x + f.y * a.y + f.z * a.z + f.w * a.w;
            s2 += f.x * b.x + f.y * b.y + f.z * b.z + f.w * b.w;
        }
#pragma unroll
        for (int off = 32; off > 0; off >>= 1) {
            s1 += __shfl_xor(s1, off);
            s2 += __shfl_xor(s2, off);
        }
        if (lane == 0) {
            const float inv800 = 1.0f / 800.0f;
            float4 bx = *(const float4*)(P.boxes + n * 4);
            float g0 = bx.x * inv800, g1 = bx.y * inv800, g2 = bx.z * inv800, g3 = bx.w * inv800;
            s1 += g0 * vs[1024] + g1 * vs[1025] + g2 * vs[1026] + g3 * vs[1027];
            s2 += g0 * vd[1024] + g1 * vd[1025] + g2 * vd[1026] + g3 * vd[1027];
            P.asrc[n * 4 + h] = s1;
            P.adst[n * 4 + h] = s2;
        }
    }
}

// ================= dispatch 3: rel, h-split into 2 half-tensors (1152 blocks) =================
#define REL_ACC(FA0, FA1, FB0, FB1, Q, W)                                           \
    {                                                                               \
        float v;                                                                    \
        v = FA0 + FB0;                                                              \
        v = fmaf(g00.x, Q.x, v); v = fmaf(g00.y, Q.y, v);                           \
        v = fmaf(g00.z, Q.z, v); v = fmaf(g00.w, Q.w, v);                           \
        acc00 = fmaf(fabsf(v), W, acc00);                                           \
        v = FA0 + FB1;                                                              \
        v = fmaf(g01.x, Q.x, v); v = fmaf(g01.y, Q.y, v);                           \
        v = fmaf(g01.z, Q.z, v); v = fmaf(g01.w, Q.w, v);                           \
        acc01 = fmaf(fabsf(v), W, acc01);                                           \
        v = FA1 + FB0;                                                              \
        v = fmaf(g10.x, Q.x, v); v = fmaf(g10.y, Q.y, v);                           \
        v = fmaf(g10.z, Q.z, v); v = fmaf(g10.w, Q.w, v);                           \
        acc10 = fmaf(fabsf(v), W, acc10);                                           \
        v = FA1 + FB1;                                                              \
        v = fmaf(g11.x, Q.x, v); v = fmaf(g11.y, Q.y, v);                           \
        v = fmaf(g11.z, Q.z, v); v = fmaf(g11.w, Q.w, v);                           \
        acc11 = fmaf(fabsf(v), W, acc11);                                           \
    }

__global__ __launch_bounds__(256) void k_rel(Params P)
{
    __shared__ __align__(16) float fas[32][68];
    __shared__ __align__(16) float fbs[32][68];
    int t = threadIdx.x;
    int u = blockIdx.x;
    int half = (u >= 576) ? 1 : 0;
    int ub = u - half * 576;
    int bx = ub % 24, by = ub / 24;
    int tx = t & 15, ty = t >> 4;
    int i0 = by * 32, j0 = bx * 32;
    int ia = i0 + ty, ib = i0 + ty + 16;
    int ja = j0 + tx, jb = j0 + tx + 16;

    float4 Bi0 = *(const float4*)(P.boxes + ia * 4);
    float4 Bi1 = *(const float4*)(P.boxes + ib * 4);
    float4 Bj0 = *(const float4*)(P.boxes + ja * 4);
    float4 Bj1 = *(const float4*)(P.boxes + jb * 4);
    float4 g00 = make_float4(fabsf(Bi0.x - Bj0.x), fabsf(Bi0.y - Bj0.y), fabsf(Bi0.z - Bj0.z), fabsf(Bi0.w - Bj0.w));
    float4 g01 = make_float4(fabsf(Bi0.x - Bj1.x), fabsf(Bi0.y - Bj1.y), fabsf(Bi0.z - Bj1.z), fabsf(Bi0.w - Bj1.w));
    float4 g10 = make_float4(fabsf(Bi1.x - Bj0.x), fabsf(Bi1.y - Bj0.y), fabsf(Bi1.z - Bj0.z), fabsf(Bi1.w - Bj0.w));
    float4 g11 = make_float4(fabsf(Bi1.x - Bj1.x), fabsf(Bi1.y - Bj1.y), fabsf(Bi1.z - Bj1.z), fabsf(Bi1.w - Bj1.w));

    float acc00 = 0.f, acc01 = 0.f, acc10 = 0.f, acc11 = 0.f;

    for (int pp = 0; pp < 2; pp++) {
        int p = half * 2 + pp;
        for (int e = t; e < 512; e += 256) {
            int r = e >> 4, cq = e & 15;
            float4 bb = *(const float4*)(P.b1 + p * 64 + cq * 4);
            float4 fv = *(const float4*)(P.fafb + (size_t)(i0 + r) * 512 + p * 64 + cq * 4);
            float4 gv = *(const float4*)(P.fafb + (size_t)(j0 + r) * 512 + 256 + p * 64 + cq * 4);
            *(float4*)&fas[r][cq * 4] = make_float4(fv.x + bb.x, fv.y + bb.y, fv.z + bb.z, fv.w + bb.w);
            *(float4*)&fbs[r][cq * 4] = gv;
        }
        __syncthreads();
        const float4* wg = P.wgt4 + p * 64;
        const float* w2 = P.w2p + p * 64;
#pragma unroll 8
        for (int hc = 0; hc < 16; hc++) {
            int h4 = hc * 4;
            float4 fa0 = *(const float4*)&fas[ty][h4];
            float4 fa1 = *(const float4*)&fas[ty + 16][h4];
            float4 fb0 = *(const float4*)&fbs[tx][h4];
            float4 fb1 = *(const float4*)&fbs[tx + 16][h4];
            float4 w2v = *(const float4*)(w2 + h4);
            float4 q0 = wg[h4], q1 = wg[h4 + 1], q2 = wg[h4 + 2], q3 = wg[h4 + 3];
            REL_ACC(fa0.x, fa1.x, fb0.x, fb1.x, q0, w2v.x);
            REL_ACC(fa0.y, fa1.y, fb0.y, fb1.y, q1, w2v.y);
            REL_ACC(fa0.z, fa1.z, fb0.z, fb1.z, q2, w2v.z);
            REL_ACC(fa0.w, fa1.w, fb0.w, fb1.w, q3, w2v.w);
        }
        __syncthreads();
    }

    float* relh = P.relm + (size_t)half * NN * NN;
    if (half == 0) {
        // linear term + b2 + diag mask carried by half 0
        float c0 = P.consts[0], c1 = P.consts[1], c2 = P.consts[2], c3 = P.consts[3], c4 = P.consts[4];
        float b2v = P.b2[0];
        float Ai0 = P.Arow[ia], Ai1 = P.Arow[ib];
        float Bja = P.Brow[ja], Bjb = P.Brow[jb];
        float lin, r00, r01, r10, r11;
        lin = Ai0 + Bja + g00.x * c0 + g00.y * c1 + g00.z * c2 + g00.w * c3 + c4;
        r00 = 0.5f * (lin + acc00) + b2v;
        lin = Ai0 + Bjb + g01.x * c0 + g01.y * c1 + g01.z * c2 + g01.w * c3 + c4;
        r01 = 0.5f * (lin + acc01) + b2v;
        lin = Ai1 + Bja + g10.x * c0 + g10.y * c1 + g10.z * c2 + g10.w * c3 + c4;
        r10 = 0.5f * (lin + acc10) + b2v;
        lin = Ai1 + Bjb + g11.x * c0 + g11.y * c1 + g11.z * c2 + g11.w * c3 + c4;
        r11 = 0.5f * (lin + acc11) + b2v;
        relh[(size_t)ia * NN + ja] = (ia == ja) ? -1e9f : r00;
        relh[(size_t)ia * NN + jb] = (ia == jb) ? -1e9f : r01;
        relh[(size_t)ib * NN + ja] = (ib == ja) ? -1e9f : r10;
        relh[(size_t)ib * NN + jb] = (ib == jb) ? -1e9f : r11;
    } else {
        // abs-half only; diag gets 0 so half-0's -1e9 dominates
        relh[(size_t)ia * NN + ja] = (ia == ja) ? 0.f : 0.5f * acc00;
        relh[(size_t)ia * NN + jb] = (ia == jb) ? 0.f : 0.5f * acc01;
        relh[(size_t)ib * NN + ja] = (ib == ja) ? 0.f : 0.5f * acc10;
        relh[(size_t)ib * NN + jb] = (ib == jb) ? 0.f : 0.5f * acc11;
    }
}

// ================= dispatch 4: topk (sums rel halves) + gat1, block per node =========
__global__ __launch_bounds__(256) void k_topkgat1(Params P)
{
    int n = blockIdx.x, t = threadIdx.x;
    __shared__ int nb[NBR_K];
    __shared__ float alpha[NBR_K][4];

    if (t < 64) {
        int lane = t;
        const float* rp0 = P.relm + (size_t)n * NN;
        const float* rp1 = P.relm + (size_t)NN * NN + (size_t)n * NN;
        float v[12];
#pragma unroll
        for (int q = 0; q < 12; q++) v[q] = rp0[q * 64 + lane] + rp1[q * 64 + lane];
        for (int kk = 0; kk < KK_TOP; kk++) {
            float best = v[0]; int bq = 0;
#pragma unroll
            for (int q = 1; q < 12; q++) {
                if (v[q] > best) { best = v[q]; bq = q; }
            }
            int bidx = bq * 64 + lane;
#pragma unroll
            for (int off = 32; off > 0; off >>= 1) {
                float ov = __shfl_xor(best, off);
                int oi = __shfl_xor(bidx, off);
                if (ov > best || (ov == best && oi < bidx)) { best = ov; bidx = oi; }
            }
            if (lane == 0) { nb[kk] = bidx; P.nbr[n * NBR_K + kk] = bidx; }
            int bl = bidx & 63, bq2 = bidx >> 6;
            if (lane == bl) {
#pragma unroll
                for (int q = 0; q < 12; q++)
                    if (q == bq2) v[q] = -INFINITY;
            }
        }
        if (lane == 0) { nb[KK_TOP] = n; P.nbr[n * NBR_K + KK_TOP] = n; }
    }
    __syncthreads();

    if (t < NBR_K * 4) {
        int k = t % NBR_K, h = t / NBR_K;
        float e = P.asrc[nb[k] * 4 + h] + P.adst[n * 4 + h];
        e = (e > 0.f) ? e : 0.2f * e;
        alpha[k][h] = e;
    }
    __syncthreads();
    if (t < 4) {
        float m = -INFINITY;
        for (int k = 0; k < NBR_K; k++) m = fmaxf(m, alpha[k][t]);
        float s = 0.f;
        for (int k = 0; k < NBR_K; k++) { float ex = expf(alpha[k][t] - m); alpha[k][t] = ex; s += ex; }
        float inv = 1.f / s;
        for (int k = 0; k < NBR_K; k++) alpha[k][t] *= inv;
    }
    __syncthreads();

    int h = t >> 6;
    float ax = 0.f, ay = 0.f, az = 0.f, aw = 0.f;
#pragma unroll 7
    for (int k = 0; k < NBR_K; k++) {
        float a = alpha[k][h];
        float4 xv = ((const float4*)(P.xp + (size_t)nb[k] * 1024))[t];
        ax = fmaf(a, xv.x, ax); ay = fmaf(a, xv.y, ay);
        az = fmaf(a, xv.z, az); aw = fmaf(a, xv.w, aw);
    }
    float4 gb = ((const float4*)P.g1b)[t];
    uint2 pk;
    pk.x = (uint_t)f2bf(fmaxf(ax + gb.x, 0.f)) | ((uint_t)f2bf(fmaxf(ay + gb.y, 0.f)) << 16);
    pk.y = (uint_t)f2bf(fmaxf(az + gb.z, 0.f)) | ((uint_t)f2bf(fmaxf(aw + gb.w, 0.f)) << 16);
    *(uint2*)(P.h1bf + (size_t)n * 1024 + t * 4) = pk;
}

// ================= dispatch 5: gat2a (192) + G3 via mfma_unit (24) =================
__global__ __launch_bounds__(256) void k_p6(Params P)
{
    __shared__ __align__(16) char smem[18432];
    int u = blockIdx.x, t = threadIdx.x;
    if (u < 192) {
        int wid = u * 4 + (t >> 6);
        int lane = t & 63;
        float s0 = 0.f, s1 = 0.f;
#pragma unroll
        for (int it = 0; it < 4; it++) {
            int k = it * 256 + lane * 4;
            uint2 pk = *(const uint2*)(P.h1bf + (size_t)wid * 1024 + k);
            float v0 = bf2f((ushort_t)(pk.x & 0xFFFF));
            float v1 = bf2f((ushort_t)(pk.x >> 16));
            float v2 = bf2f((ushort_t)(pk.y & 0xFFFF));
            float v3 = bf2f((ushort_t)(pk.y >> 16));
            float4 w0 = *(const float4*)(P.g2W + k * 2);
            float4 w1 = *(const float4*)(P.g2W + k * 2 + 4);
            s0 += v0 * w0.x + v1 * w0.z + v2 * w1.x + v3 * w1.z;
            s1 += v0 * w0.y + v1 * w0.w + v2 * w1.y + v3 * w1.w;
        }
#pragma unroll
        for (int off = 32; off > 0; off >>= 1) { s0 += __shfl_down(s0, off); s1 += __shfl_down(s1, off); }
        if (lane == 0) {
            P.xp2[wid * 2 + 0] = s0; P.xp2[wid * 2 + 1] = s1;
            P.aux2[wid * 2 + 0] = s0 * P.g2as[0] + s1 * P.g2as[1];
            P.aux2[wid * 2 + 1] = s0 * P.g2ad[0] + s1 * P.g2ad[1];
        }
    } else {
        int v = u - 192;
        mfma_unit(v & 1, v >> 1, P.h1bf, P.btR, P.hid, 128, 2,
                  P.boxes, P.rW1 + (size_t)1024 * 128, P.rb1, t, smem);
    }
}

// ================= dispatch 6: gat2b wave-per-node (192) + decode (3) =================
__global__ __launch_bounds__(256) void k_p7(Params P)
{
    __shared__ __align__(16) float rw2s[512];
    int u = blockIdx.x, t = threadIdx.x;
    if (u < 192) {
        int n = u * 4 + (t >> 6);
        int lane = t & 63;
        float adstv = P.aux2[n * 2 + 1];
        float e = -INFINITY, x0 = 0.f, x1 = 0.f;
        if (lane < NBR_K) {
            int nbk = P.nbr[n * NBR_K + lane];
            float vv = P.aux2[nbk * 2 + 0] + adstv;
            e = (vv > 0.f) ? vv : 0.2f * vv;
            x0 = P.xp2[nbk * 2 + 0];
            x1 = P.xp2[nbk * 2 + 1];
        }
        float m = e;
#pragma unroll
        for (int off = 32; off > 0; off >>= 1) m = fmaxf(m, __shfl_xor(m, off));
        float ex = (lane < NBR_K) ? expf(e - m) : 0.f;
        float ssum = ex, o0 = ex * x0, o1 = ex * x1;
#pragma unroll
        for (int off = 32; off > 0; off >>= 1) {
            ssum += __shfl_xor(ssum, off);
            o0 += __shfl_xor(o0, off);
            o1 += __shfl_xor(o1, off);
        }
        if (lane == 0) {
            float inv = 1.f / ssum;
            P.out[n * 6 + 0] = o0 * inv + P.g2b[0];
            P.out[n * 6 + 1] = o1 * inv + P.g2b[1];
        }
        return;
    }
    // decode: thread per node, rW2 staged in LDS
    *(float2*)&rw2s[t * 2] = *(const float2*)(P.rW2 + t * 2);
    __syncthreads();
    int n = (u - 192) * 256 + t;
    const float4* hrow = (const float4*)(P.hid + (size_t)n * 128);
    float d0 = 0.f, d1 = 0.f, d2 = 0.f, d3 = 0.f;
#pragma unroll 8
    for (int k4 = 0; k4 < 32; k4++) {
        float4 h = hrow[k4];
        const float* wv = &rw2s[k4 * 16];
        d0 = fmaf(h.x, wv[0], d0);  d1 = fmaf(h.x, wv[1], d1);
        d2 = fmaf(h.x, wv[2], d2);  d3 = fmaf(h.x, wv[3], d3);
        d0 = fmaf(h.y, wv[4], d0);  d1 = fmaf(h.y, wv[5], d1);
        d2 = fmaf(h.y, wv[6], d2);  d3 = fmaf(h.y, wv[7], d3);
        d0 = fmaf(h.z, wv[8], d0);  d1 = fmaf(h.z, wv[9], d1);
        d2 = fmaf(h.z, wv[10], d2); d3 = fmaf(h.z, wv[11], d3);
        d0 = fmaf(h.w, wv[12], d0); d1 = fmaf(h.w, wv[13], d1);
        d2 = fmaf(h.w, wv[14], d2); d3 = fmaf(h.w, wv[15], d3);
    }
    d0 += P.rb2[0]; d1 += P.rb2[1]; d2 += P.rb2[2]; d3 += P.rb2[3];
    float4 bx = *(const float4*)(P.boxes + n * 4);
    float pw = bx.z - bx.x, ph = bx.w - bx.y;
    float pcx = bx.x + 0.5f * pw, pcy = bx.y + 0.5f * ph;
    float gcx = d0 * pw + pcx, gcy = d1 * ph + pcy;
    float gw = expf(d2) * pw, gh = expf(d3) * ph;
    P.out[n * 6 + 2] = gcx - 0.5f * gw;
    P.out[n * 6 + 3] = gcy - 0.5f * gh;
    P.out[n * 6 + 4] = gcx + 0.5f * gw;
    P.out[n * 6 + 5] = gcy + 0.5f * gh;
}

extern "C" void kernel_launch(void* const* d_in, const int* in_sizes, int n_in,
                              void* d_out, int out_size, void* d_ws, size_t ws_size,
                              hipStream_t stream)
{
    Params P;
    P.feats = (const float*)d_in[0];
    P.boxes = (const float*)d_in[1];
    P.W1    = (const float*)d_in[2];
    P.b1    = (const float*)d_in[3];
    P.W2    = (const float*)d_in[4];
    P.b2    = (const float*)d_in[5];
    P.g1W   = (const float*)d_in[6];
    P.g1as  = (const float*)d_in[7];
    P.g1ad  = (const float*)d_in[8];
    P.g1b   = (const float*)d_in[9];
    P.g2W   = (const float*)d_in[10];
    P.g2as  = (const float*)d_in[11];
    P.g2ad  = (const float*)d_in[12];
    P.g2b   = (const float*)d_in[13];
    P.rW1   = (const float*)d_in[14];
    P.rb1   = (const float*)d_in[15];
    P.rW2   = (const float*)d_in[16];
    P.rb2   = (const float*)d_in[17];
    P.out   = (float*)d_out;

    float* ws = (float*)d_ws;
    P.fafb  = ws;                      // 768*512
    P.xp    = P.fafb + 393216;         // 768*1024
    P.relm  = P.xp + 786432;           // 2 * 768*768 (two h-halves)
    P.hid   = P.relm + 2 * 589824;     // 768*128
    P.Arow  = P.hid + 98304;           // 768
    P.Brow  = P.Arow + 768;            // 768
    P.asrc  = P.Brow + 768;            // 3072
    P.adst  = P.asrc + 3072;           // 3072
    P.xp2   = P.adst + 3072;           // 1536
    P.aux2  = P.xp2 + 1536;            // 1536
    P.wgt4  = (float4*)(P.aux2 + 1536);// 256 float4
    P.w2p   = (float*)(P.wgt4 + 256);  // 256
    P.consts= P.w2p + 256;             // 8
    P.va    = P.consts + 8;            // 1024
    P.vb    = P.va + 1024;             // 1024
    P.av    = P.vb + 1024;             // 8224
    P.nbr   = (int*)(P.av + 8224);     // 768*21
    P.featsbf = (ushort_t*)(P.nbr + 16128);  // 768*1024
    P.btAB    = P.featsbf + 786432;          // 512*1024
    P.btG     = P.btAB + 524288;             // 1024*1024
    P.btR     = P.btG + 1048576;             // 128*1024
    P.h1bf    = P.btR + 131072;              // 768*1024

    k_prep    <<<dim3(3369), dim3(256), 0, stream>>>(P);
    k_gemms   <<<dim3(1248), dim3(256), 0, stream>>>(P);
    k_rel     <<<dim3(1152), dim3(256), 0, stream>>>(P);
    k_topkgat1<<<dim3(768),  dim3(256), 0, stream>>>(P);
    k_p6      <<<dim3(216),  dim3(256), 0, stream>>>(P);
    k_p7      <<<dim3(195),  dim3(256), 0, stream>>>(P);
}